// Round 7
// baseline (116.589 us; speedup 1.0000x reference)
//
#include <hip/hip_runtime.h>

typedef _Float16 half8 __attribute__((ext_vector_type(8)));
typedef __fp16 fp16x2 __attribute__((ext_vector_type(2)));
typedef float f32x4 __attribute__((ext_vector_type(4)));

static __device__ __forceinline__ unsigned pkrtz(float a, float b) {
    union { fp16x2 v; unsigned u; } cv;
    cv.v = __builtin_amdgcn_cvt_pkrtz(a, b);
    return cv.u;
}

// ---------------- prep: pack W1/b1/W2/b2 into f16 MFMA B-fragments in d_ws ----
// Slot convention (both A and B): frag slot (g = lane>>4, r = reg 0..7) <-> k = 8g + r
// (any consistent bijection works since A and B use the same one).
// B1: 3 col-tiles (N=40 -> 48), slots t in [0,192): tile n=t>>6, lane l=t&63,
//     col j = n*16 + (l&15), k = 8*(l>>4)+r ; k==10 carries b1[j] (A has 1.0 there).
// B2: 2 K-frags (K=40 -> 64), slots i in [0,128): frag f=i>>6, lane l=i&63,
//     col o = l&15 (valid o<4), k = 32f + 8*(l>>4)+r ; k==40 carries b2[o].
__global__ void prep_kernel(const float* __restrict__ W1, const float* __restrict__ b1,
                            const float* __restrict__ W2, const float* __restrict__ b2,
                            uint4* __restrict__ ws) {
    const int t = threadIdx.x;
    if (t < 192) {
        const int n = t >> 6, l = t & 63;
        const int j = n * 16 + (l & 15);
        const int g = l >> 4;
        float v[8];
        #pragma unroll
        for (int r = 0; r < 8; ++r) {
            const int k = 8 * g + r;
            float val = 0.f;
            if (j < 40) {
                if (k < 10) val = W1[j * 10 + k];
                else if (k == 10) val = b1[j];
            }
            v[r] = val;
        }
        uint4 u;
        u.x = pkrtz(v[0], v[1]); u.y = pkrtz(v[2], v[3]);
        u.z = pkrtz(v[4], v[5]); u.w = pkrtz(v[6], v[7]);
        ws[t] = u;
    } else if (t < 320) {
        const int i = t - 192;
        const int f = i >> 6, l = i & 63;
        const int o = l & 15, g = l >> 4;
        float v[8];
        #pragma unroll
        for (int r = 0; r < 8; ++r) {
            const int k = 32 * f + 8 * g + r;
            float val = 0.f;
            if (o < 4) {
                if (k < 40) val = W2[o * 40 + k];
                else if (k == 40) val = b2[o];
            }
            v[r] = val;
        }
        uint4 u;
        u.x = pkrtz(v[0], v[1]); u.y = pkrtz(v[2], v[3]);
        u.z = pkrtz(v[4], v[5]); u.w = pkrtz(v[6], v[7]);
        ws[t] = u;
    }
}

// ---------------- main: 256 edges/block, 64 edges/wave (4 MFMA M-tiles) -------
// LDS map (dwords):
//   [0,4096)     shA : per-wave A-fragments, w*1024 + tile*256 + lane*4
//   [4096,5376)  shB : packed B slots (B1: 0..191, B2: 192..319)
//   [5376,7424)  shH : per-wave H (layer1 out as layer2 A-frags), w*512 + frag*256 + lane*4
//   [7424,9216)  shE : per-wave out/e_tilde staging, w*448
#define SMEM_DW 9216

__global__ __launch_bounds__(256) void edge_mlp_mfma_kernel(
    const float* __restrict__ x,
    const float* __restrict__ w,
    const int* __restrict__ src,
    const int* __restrict__ dst,
    const uint4* __restrict__ ws,
    float* __restrict__ w_out,
    float* __restrict__ e_tilde,
    int E)
{
    __shared__ __align__(16) unsigned smem[SMEM_DW];
    const int t   = threadIdx.x;
    const int wid = t >> 6;
    const int s   = t & 63;
    const int tl  = s >> 4;     // this thread's edge tile within its wave
    const int row = s & 15;     // row within tile

    unsigned* shB = smem + 4096;
    unsigned* myA = smem + wid * 1024;
    unsigned* myH = smem + 5376 + wid * 512;
    unsigned* myE = smem + 7424 + wid * 448;

    // load packed weight fragments (cross-wave; barrier below)
    for (int i = t; i < 320; i += 256)
        ((uint4*)shB)[i] = ws[i];

    // wave-local zero init of A and H pads
    #pragma unroll
    for (int i = 0; i < 16; ++i) myA[s * 16 + i] = 0;
    #pragma unroll
    for (int i = 0; i < 8; ++i) myH[s * 8 + i] = 0;
    // H frag2 slot k=40 := 1.0h for all 16 rows (layer2 bias row, never overwritten)
    if (s >= 16 && s < 32) myH[256 + s * 4] = 0x00003C00u;

    // phase 1: gather + pack this edge's A-row (k0..7 | k8,k9,1.0,pad)
    const int e = blockIdx.x * 256 + t;
    float m0=0,m1=0,m2=0,m3=0,m4=0,m5=0,m6=0,m7=0,m8=0,m9=0;
    if (e < E) {
        const int si = src[e], di = dst[e];
        m0 = x[3*si]; m1 = x[3*si+1]; m2 = x[3*si+2];
        m3 = x[3*di]; m4 = x[3*di+1]; m5 = x[3*di+2];
        const float4 wv = ((const float4*)w)[e];
        m6 = wv.x; m7 = wv.y; m8 = wv.z; m9 = wv.w;
    }
    {
        uint4 a;
        a.x = pkrtz(m0, m1); a.y = pkrtz(m2, m3);
        a.z = pkrtz(m4, m5); a.w = pkrtz(m6, m7);
        *(uint4*)&myA[tl * 256 + row * 4] = a;
        uint2 b;
        b.x = pkrtz(m8, m9); b.y = 0x00003C00u;   // k=10 := 1.0 (bias slot)
        *(uint2*)&myA[tl * 256 + (16 + row) * 4] = b;
    }
    __syncthreads();

    const f32x4 zero4 = {0.f, 0.f, 0.f, 0.f};
    const half8 b1f0 = *(const half8*)&shB[(  0 + s) * 4];
    const half8 b1f1 = *(const half8*)&shB[( 64 + s) * 4];
    const half8 b1f2 = *(const half8*)&shB[(128 + s) * 4];
    const half8 b2f0 = *(const half8*)&shB[(192 + s) * 4];
    const half8 b2f1 = *(const half8*)&shB[(256 + s) * 4];

    _Float16* hH = (_Float16*)myH;   // 1024 halves; frag*512 + (g*16+row)*8 + r
    const int srow = (s >> 4) * 4;   // C/D row base: row = srow + reg
    const int c    = s & 15;         // C/D col

    #pragma unroll
    for (int tt = 0; tt < 4; ++tt) {
        const half8 av = *(const half8*)&myA[tt * 256 + s * 4];
        f32x4 c0 = __builtin_amdgcn_mfma_f32_16x16x32_f16(av, b1f0, zero4, 0, 0, 0);
        f32x4 c1 = __builtin_amdgcn_mfma_f32_16x16x32_f16(av, b1f1, zero4, 0, 0, 0);
        f32x4 c2 = __builtin_amdgcn_mfma_f32_16x16x32_f16(av, b1f2, zero4, 0, 0, 0);
        __builtin_amdgcn_sched_barrier(0);
        // ReLU + cvt + scatter into H (layer2 A-fragment layout, k = hidden j)
        #pragma unroll
        for (int q = 0; q < 4; ++q) {
            const int rr = srow + q;
            // n=0: j = c (0..15): frag0, g=c>>3, r=c&7
            hH[(c >> 3) * 128 + rr * 8 + (c & 7)] = (_Float16)fmaxf(c0[q], 0.f);
            // n=1: j = 16+c (16..31): frag0, g=2+(c>>3)
            hH[(2 + (c >> 3)) * 128 + rr * 8 + (c & 7)] = (_Float16)fmaxf(c1[q], 0.f);
            // n=2: j = 32+c (valid j<40 -> c<8): frag1, g=0, r=c; c>=8 would
            // clobber the k=40 bias-one slot, so mask.
            if (c < 8)
                hH[512 + rr * 8 + c] = (_Float16)fmaxf(c2[q], 0.f);
        }
        __builtin_amdgcn_sched_barrier(0);
        const half8 a2a = *(const half8*)&myH[s * 4];
        const half8 a2b = *(const half8*)&myH[256 + s * 4];
        f32x4 oo = __builtin_amdgcn_mfma_f32_16x16x32_f16(a2a, b2f0, zero4, 0, 0, 0);
        oo = __builtin_amdgcn_mfma_f32_16x16x32_f16(a2b, b2f1, oo, 0, 0, 0);
        __builtin_amdgcn_sched_barrier(0);
        // D2 -> per-edge staging (edge-local idx = tt*16 + rr, col o = c)
        if (c < 4) {
            #pragma unroll
            for (int q = 0; q < 4; ++q)
                myE[(tt * 16 + srow + q) * 4 + c] = __float_as_uint(oo[q]);
        }
        __builtin_amdgcn_sched_barrier(0);
    }

    // read own edge's w_out (coalesced b128), store, then e_tilde staging
    float4 wo;
    {
        union { uint4 u; float4 f; } cv;
        cv.u = *(uint4*)&myE[s * 4];
        wo = cv.f;
    }
    if (e < E) ((float4*)w_out)[e] = wo;
    __builtin_amdgcn_sched_barrier(0);
    myE[s * 7 + 0] = __float_as_uint(m0);
    myE[s * 7 + 1] = __float_as_uint(m1);
    myE[s * 7 + 2] = __float_as_uint(m2);
    myE[s * 7 + 3] = __float_as_uint(wo.x);
    myE[s * 7 + 4] = __float_as_uint(wo.y);
    myE[s * 7 + 5] = __float_as_uint(wo.z);
    myE[s * 7 + 6] = __float_as_uint(wo.w);
    __builtin_amdgcn_sched_barrier(0);
    const int base_e = blockIdx.x * 256 + wid * 64;
    const int nvalid = (E - base_e < 64 ? E - base_e : 64) * 7;
    const long long fbase = (long long)base_e * 7;
    #pragma unroll
    for (int k = 0; k < 7; ++k) {
        const int idx = s + 64 * k;
        if (idx < nvalid) e_tilde[fbase + idx] = __uint_as_float(myE[idx]);
    }
}

extern "C" void kernel_launch(void* const* d_in, const int* in_sizes, int n_in,
                              void* d_out, int out_size, void* d_ws, size_t ws_size,
                              hipStream_t stream) {
    const float* x  = (const float*)d_in[0];
    const float* w  = (const float*)d_in[1];
    const float* W1 = (const float*)d_in[2];
    const float* b1 = (const float*)d_in[3];
    const float* W2 = (const float*)d_in[4];
    const float* b2 = (const float*)d_in[5];
    const int* src  = (const int*)d_in[6];
    const int* dst  = (const int*)d_in[7];

    const int E = in_sizes[6];

    float* w_out   = (float*)d_out;
    float* e_tilde = w_out + (size_t)E * 4;
    uint4* ws      = (uint4*)d_ws;

    prep_kernel<<<1, 320, 0, stream>>>(W1, b1, W2, b2, ws);

    const int nblocks = (E + 255) / 256;
    edge_mlp_mfma_kernel<<<nblocks, 256, 0, stream>>>(
        x, w, src, dst, ws, w_out, e_tilde, E);
}

// Round 9
// 100.282 us; speedup vs baseline: 1.1626x; 1.1626x over previous
//
#include <hip/hip_runtime.h>

typedef __fp16 h2 __attribute__((ext_vector_type(2)));

static __device__ __forceinline__ unsigned pkrtz(float a, float b) {
    union { h2 v; unsigned u; } cv;
    cv.v = __builtin_amdgcn_cvt_pkrtz(a, b);
    return cv.u;
}
static __device__ __forceinline__ h2 as_h2(unsigned u) {
    union { unsigned u; h2 v; } cv; cv.u = u; return cv.v;
}

// ---- prep: pack weights into f16-pair dwords in d_ws -------------------------
// Layout (dwords):
//   [j*6 + i]      i<5 : (W1[j][2i], W1[j][2i+1]) f16 pair       (j in 0..39)
//   [j*6 + 5]          : b1[j] as f32 bits
//   [240 + p*4+o]      : (W2[o][2p], W2[o][2p+1]) f16 pair       (p in 0..19)
//   [320 + o]          : b2[o] as f32 bits
__global__ void prep_kernel(const float* __restrict__ W1, const float* __restrict__ b1,
                            const float* __restrict__ W2, const float* __restrict__ b2,
                            unsigned* __restrict__ ws) {
    const int t = threadIdx.x;
    if (t < 40) {
        #pragma unroll
        for (int i = 0; i < 5; ++i)
            ws[t * 6 + i] = pkrtz(W1[t * 10 + 2 * i], W1[t * 10 + 2 * i + 1]);
        ws[t * 6 + 5] = __float_as_uint(b1[t]);
    } else if (t < 60) {
        const int p = t - 40;
        #pragma unroll
        for (int o = 0; o < 4; ++o)
            ws[240 + p * 4 + o] = pkrtz(W2[o * 40 + 2 * p], W2[o * 40 + 2 * p + 1]);
    } else if (t < 64) {
        ws[320 + (t - 60)] = __float_as_uint(b2[t - 60]);
    }
}

// ---- main: 1 thread per edge; weights via uniform (SGPR) loads ---------------
#define TPB 256

__global__ __launch_bounds__(TPB) void edge_mlp_dot2_kernel(
    const float* __restrict__ x,
    const float* __restrict__ w,
    const int* __restrict__ src,
    const int* __restrict__ dst,
    const unsigned* __restrict__ W,   // packed weights (uniform access -> SGPR)
    float* __restrict__ w_out,
    float* __restrict__ e_tilde,
    int E)
{
    __shared__ float s_et[4][64 * 7];   // per-wave e_tilde staging

    const int t    = threadIdx.x;
    const int wave = t >> 6;
    const int lane = t & 63;
    const int e    = blockIdx.x * TPB + t;

    float m0 = 0.f, m1 = 0.f, m2 = 0.f;
    h2 vm0 = as_h2(0), vm1 = as_h2(0), vm2 = as_h2(0), vm3 = as_h2(0), vm4 = as_h2(0);

    if (e < E) {
        const int si = src[e], di = dst[e];
        m0 = x[3 * si]; m1 = x[3 * si + 1]; m2 = x[3 * si + 2];
        const float d0 = x[3 * di], d1 = x[3 * di + 1], d2 = x[3 * di + 2];
        const float4 wv = ((const float4*)w)[e];
        vm0 = as_h2(pkrtz(m0, m1));
        vm1 = as_h2(pkrtz(m2, d0));
        vm2 = as_h2(pkrtz(d1, d2));
        vm3 = as_h2(pkrtz(wv.x, wv.y));
        vm4 = as_h2(pkrtz(wv.z, wv.w));
    }

    float o0 = __uint_as_float(W[320]);
    float o1 = __uint_as_float(W[321]);
    float o2 = __uint_as_float(W[322]);
    float o3 = __uint_as_float(W[323]);

    #pragma unroll
    for (int jp = 0; jp < 20; ++jp) {
        const int j0 = 2 * jp, j1 = 2 * jp + 1;
        float h0v = __uint_as_float(W[j0 * 6 + 5]);
        float h1v = __uint_as_float(W[j1 * 6 + 5]);
        h0v = __builtin_amdgcn_fdot2(vm0, as_h2(W[j0 * 6 + 0]), h0v, false);
        h1v = __builtin_amdgcn_fdot2(vm0, as_h2(W[j1 * 6 + 0]), h1v, false);
        h0v = __builtin_amdgcn_fdot2(vm1, as_h2(W[j0 * 6 + 1]), h0v, false);
        h1v = __builtin_amdgcn_fdot2(vm1, as_h2(W[j1 * 6 + 1]), h1v, false);
        h0v = __builtin_amdgcn_fdot2(vm2, as_h2(W[j0 * 6 + 2]), h0v, false);
        h1v = __builtin_amdgcn_fdot2(vm2, as_h2(W[j1 * 6 + 2]), h1v, false);
        h0v = __builtin_amdgcn_fdot2(vm3, as_h2(W[j0 * 6 + 3]), h0v, false);
        h1v = __builtin_amdgcn_fdot2(vm3, as_h2(W[j1 * 6 + 3]), h1v, false);
        h0v = __builtin_amdgcn_fdot2(vm4, as_h2(W[j0 * 6 + 4]), h0v, false);
        h1v = __builtin_amdgcn_fdot2(vm4, as_h2(W[j1 * 6 + 4]), h1v, false);
        h0v = fmaxf(h0v, 0.f);
        h1v = fmaxf(h1v, 0.f);
        const h2 hp = as_h2(pkrtz(h0v, h1v));
        o0 = __builtin_amdgcn_fdot2(hp, as_h2(W[240 + jp * 4 + 0]), o0, false);
        o1 = __builtin_amdgcn_fdot2(hp, as_h2(W[240 + jp * 4 + 1]), o1, false);
        o2 = __builtin_amdgcn_fdot2(hp, as_h2(W[240 + jp * 4 + 2]), o2, false);
        o3 = __builtin_amdgcn_fdot2(hp, as_h2(W[240 + jp * 4 + 3]), o3, false);
    }

    if (e < E) ((float4*)w_out)[e] = make_float4(o0, o1, o2, o3);

    // e_tilde staging -> coalesced stores (same scheme as measured-clean round 0)
    float* sw = s_et[wave];
    sw[lane * 7 + 0] = m0;
    sw[lane * 7 + 1] = m1;
    sw[lane * 7 + 2] = m2;
    sw[lane * 7 + 3] = o0;
    sw[lane * 7 + 4] = o1;
    sw[lane * 7 + 5] = o2;
    sw[lane * 7 + 6] = o3;
    __syncthreads();

    const int base_e  = blockIdx.x * TPB + wave * 64;
    const int nvalid  = (E - base_e < 64 ? (E - base_e) : 64) * 7;
    const long long fbase = (long long)base_e * 7;
    #pragma unroll
    for (int k = 0; k < 7; ++k) {
        const int idx = lane + 64 * k;
        if (idx < nvalid) e_tilde[fbase + idx] = sw[idx];
    }
}

extern "C" void kernel_launch(void* const* d_in, const int* in_sizes, int n_in,
                              void* d_out, int out_size, void* d_ws, size_t ws_size,
                              hipStream_t stream) {
    const float* x  = (const float*)d_in[0];
    const float* w  = (const float*)d_in[1];
    const float* W1 = (const float*)d_in[2];
    const float* b1 = (const float*)d_in[3];
    const float* W2 = (const float*)d_in[4];
    const float* b2 = (const float*)d_in[5];
    const int* src  = (const int*)d_in[6];
    const int* dst  = (const int*)d_in[7];

    const int E = in_sizes[6];

    float* w_out   = (float*)d_out;
    float* e_tilde = w_out + (size_t)E * 4;
    unsigned* ws   = (unsigned*)d_ws;

    prep_kernel<<<1, 64, 0, stream>>>(W1, b1, W2, b2, ws);

    const int nblocks = (E + TPB - 1) / TPB;
    edge_mlp_dot2_kernel<<<nblocks, TPB, 0, stream>>>(
        x, w, src, dst, ws, w_out, e_tilde, E);
}